// Round 12
// baseline (27.183 us; speedup 1.0000x reference)
//
#include <hip/hip_runtime.h>
#include <hip/hip_bf16.h>
#include <math.h>

// FragmentEmbedder, round 12: R11 layout + 2-point ILP per thread.
//
// R11 post-mortem: request-minimized layout (3 req/pt) gave 25.3 us, but
// time stopped scaling with request count -> latency-bound on the dependent
// gene->gather chain, not request-throughput-bound. R12: each thread owns
// TWO independent points (n, n+H); the two gather chains overlap in flight,
// halving latency exposure per point and halving wave count.
//
// Table layout per gene (128 B, from R11):
//   @ +16c       : uint4 {(i=0,x),(i=1,x),(i=0,y),(i=1,y)} f16 pairs, c=0..4
//   @ +80+8c     : uint2 { half2(Lx,Ly), f32 bias' }
//   Lx,Ly = sum_{i>=2} f_i*w (sin-linearized, pre-summed f32 -> f16)
//   bias' = bias + sum_{i>=2} cos-folded weights

#define N_GENES 5000
#define BLK_BYTES 128
#define W5_BYTES ((size_t)N_GENES * BLK_BYTES)    // 640 KB

typedef _Float16 half2_t __attribute__((ext_vector_type(2)));

#if __has_builtin(__builtin_amdgcn_fdot2)
__device__ __forceinline__ float fdot2f(half2_t a, half2_t b, float c) {
    return __builtin_amdgcn_fdot2(a, b, c, false);
}
#else
__device__ __forceinline__ float fdot2f(half2_t a, half2_t b, float c) {
    return fmaf((float)a.x, (float)b.x, fmaf((float)a.y, (float)b.y, c));
}
#endif

__device__ __forceinline__ half2_t pkrtz(float a, float b) {
    auto r = __builtin_amdgcn_cvt_pkrtz(a, b);
    union { decltype(r) s; half2_t d; } v; v.s = r; return v.d;
}
__device__ __forceinline__ half2_t u2h(unsigned int u) {
    union { unsigned int i; half2_t h; } v; v.i = u; return v.h;
}
__device__ __forceinline__ float u2f(unsigned int u) {
    union { unsigned int i; float f; } v; v.i = u; return v.f;
}
__device__ __forceinline__ unsigned int h2u(_Float16 lo, _Float16 hi) {
    union { _Float16 h[2]; unsigned int i; } v; v.h[0] = lo; v.h[1] = hi; return v.i;
}
__device__ __forceinline__ unsigned int f2u(float f) {
    union { float f; unsigned int i; } v; v.f = f; return v.i;
}

// f_i = 10^{-0.6*(i+1)}, i = 0..9  (radians)
__device__ __constant__ float FRc[10] = {
    0.251188643150958f, 0.0630957344480193f, 0.0158489319246111f,
    0.00398107170553497f, 0.001f, 0.000251188643150958f,
    6.30957344480193e-05f, 1.58489319246111e-05f, 3.98107170553497e-06f, 1e-06f
};

// ---------------- pre-pass: repack weights (R11 layout) ----------------
__global__ __launch_bounds__(256) void build_w5(
    const float* __restrict__ w,     // [5000, 40, 5]
    const float* __restrict__ bias,  // [5000, 5]
    unsigned char* __restrict__ w5)
{
    int t = blockIdx.x * 256 + threadIdx.x;
    if (t >= N_GENES * 5) return;
    int g = t / 5, c = t - 5 * g;

    const float* base = w + (size_t)g * 200 + c;   // w[g][a][c] = base[a*5]

    uint4 S;
    S.x = h2u((_Float16)base[0 * 5],  (_Float16)base[1 * 5]);    // i=0, x
    S.y = h2u((_Float16)base[2 * 5],  (_Float16)base[3 * 5]);    // i=1, x
    S.z = h2u((_Float16)base[20 * 5], (_Float16)base[21 * 5]);   // i=0, y
    S.w = h2u((_Float16)base[22 * 5], (_Float16)base[23 * 5]);   // i=1, y

    float Lx = 0.f, Ly = 0.f;
    float bp = bias[(size_t)g * 5 + c];
#pragma unroll
    for (int i = 2; i < 10; ++i) {
        Lx += FRc[i] * base[(2 * i) * 5];
        Ly += FRc[i] * base[(20 + 2 * i) * 5];
        bp += base[(2 * i + 1) * 5] + base[(21 + 2 * i) * 5];
    }

    unsigned char* blk = w5 + (size_t)g * BLK_BYTES;
    *reinterpret_cast<uint4*>(blk + c * 16) = S;
    uint2 L;
    L.x = h2u((_Float16)Lx, (_Float16)Ly);
    L.y = f2u(bp);
    *reinterpret_cast<uint2*>(blk + 80 + c * 8) = L;
}

// sin/cos pair for freq I packed to half2 (I = 0,1 only; I>=2 folded away)
template <int I>
__device__ __forceinline__ half2_t sc_pack(float x) {
    float t = x * FRc[I];
    float s, co;
    if (I == 0) {
        s  = __sinf(t);                                            // |t| <= ~1.4
        co = __cosf(t);
    } else {                                                       // |t| <= 0.36
        float u = t * t;
        s  = t * fmaf(u, fmaf(u, 1.f / 120.f, -1.f / 6.f), 1.f);   // err < 5e-5
        co = fmaf(u, fmaf(u, 1.f / 24.f, -0.5f), 1.f);             // err < 1e-5
    }
    return pkrtz(s, co);
}

__device__ __forceinline__ float point_dot(float x, float y, uint4 S, uint2 L) {
    half2_t sx0 = sc_pack<0>(x), sx1 = sc_pack<1>(x);
    half2_t sy0 = sc_pack<0>(y), sy1 = sc_pack<1>(y);
    half2_t xy  = pkrtz(x, y);
    float acc = u2f(L.y);                 // bias' (+ all folded cos terms)
    acc = fdot2f(sx0, u2h(S.x), acc);
    acc = fdot2f(sx1, u2h(S.y), acc);
    acc = fdot2f(sy0, u2h(S.z), acc);
    acc = fdot2f(sy1, u2h(S.w), acc);
    acc = fdot2f(xy,  u2h(L.x), acc);     // all i>=2 terms, pre-summed
    return 1.f / (1.f + __expf(-acc));
}

// ---------------- main: 5 lanes/point, 2 points/thread ----------------
__global__ __launch_bounds__(256) void frag_embed5x2(
    const float* __restrict__ coords,        // [N,2] flat
    const int*   __restrict__ gene_ix,       // [N]
    const unsigned char* __restrict__ w5,    // [5000] x 128 B blocks
    float*       __restrict__ out,           // [N, 5]
    unsigned int N,
    unsigned int H)                          // (N+1)/2
{
    unsigned int tid = blockIdx.x * 256u + threadIdx.x;
    unsigned int p = tid / 5u;           // pair index (magic-mul)
    unsigned int c = tid - p * 5u;       // output channel, 0..4
    if (p >= H) return;

    const unsigned int n0 = p;
    const unsigned int n1 = p + H;
    const unsigned int n1c = (n1 < N) ? n1 : (N - 1);   // clamp, predicate store

    // Issue both points' streaming loads together (independent chains).
    const float x0 = __builtin_nontemporal_load(coords + 2 * (size_t)n0);
    const float y0 = __builtin_nontemporal_load(coords + 2 * (size_t)n0 + 1);
    const int   g0 = __builtin_nontemporal_load(gene_ix + n0);
    const float x1 = __builtin_nontemporal_load(coords + 2 * (size_t)n1c);
    const float y1 = __builtin_nontemporal_load(coords + 2 * (size_t)n1c + 1);
    const int   g1 = __builtin_nontemporal_load(gene_ix + n1c);

    // Issue all four gathers together (2 lines per point, overlapped).
    const unsigned char* __restrict__ b0 = w5 + (size_t)g0 * BLK_BYTES;
    const unsigned char* __restrict__ b1 = w5 + (size_t)g1 * BLK_BYTES;
    const uint4 S0 = *reinterpret_cast<const uint4*>(b0 + c * 16);
    const uint2 L0 = *reinterpret_cast<const uint2*>(b0 + 80 + c * 8);
    const uint4 S1 = *reinterpret_cast<const uint4*>(b1 + c * 16);
    const uint2 L1 = *reinterpret_cast<const uint2*>(b1 + 80 + c * 8);

    const float r0 = point_dot(x0, y0, S0, L0);
    __builtin_nontemporal_store(r0, out + (size_t)n0 * 5 + c);

    const float r1 = point_dot(x1, y1, S1, L1);
    if (n1 < N)
        __builtin_nontemporal_store(r1, out + (size_t)n1 * 5 + c);
}

// ---------------- fallback if d_ws too small ----------------
__global__ __launch_bounds__(256) void frag_embed_fallback(
    const float* __restrict__ coords, const int* __restrict__ gene_ix,
    const float* __restrict__ weight, const float* __restrict__ bias,
    float* __restrict__ out, int N)
{
    int n = blockIdx.x * blockDim.x + threadIdx.x;
    if (n >= N) return;
    const float cxo = coords[2 * (size_t)n];
    const float cyo = coords[2 * (size_t)n + 1];
    const int g = gene_ix[n];
    float emb[40];
    float c2[2] = { cxo, cyo };
#pragma unroll
    for (int d = 0; d < 2; ++d)
#pragma unroll
        for (int i = 0; i < 10; ++i) {
            float t = c2[d] * FRc[i];
            emb[d * 20 + 2 * i]     = __sinf(t);
            emb[d * 20 + 2 * i + 1] = __cosf(t);
        }
    const float4* wp = reinterpret_cast<const float4*>(weight + (size_t)g * 200);
    float acc[5];
#pragma unroll
    for (int c = 0; c < 5; ++c) acc[c] = bias[(size_t)g * 5 + c];
#pragma unroll
    for (int j = 0; j < 50; ++j) {
        float4 wv = wp[j];
        const int k = 4 * j;
        acc[(k + 0) % 5] = fmaf(emb[(k + 0) / 5], wv.x, acc[(k + 0) % 5]);
        acc[(k + 1) % 5] = fmaf(emb[(k + 1) / 5], wv.y, acc[(k + 1) % 5]);
        acc[(k + 2) % 5] = fmaf(emb[(k + 2) / 5], wv.z, acc[(k + 2) % 5]);
        acc[(k + 3) % 5] = fmaf(emb[(k + 3) / 5], wv.w, acc[(k + 3) % 5]);
    }
    size_t ob = (size_t)n * 5;
#pragma unroll
    for (int c = 0; c < 5; ++c)
        out[ob + c] = 1.f / (1.f + __expf(-acc[c]));
}

extern "C" void kernel_launch(void* const* d_in, const int* in_sizes, int n_in,
                              void* d_out, int out_size, void* d_ws, size_t ws_size,
                              hipStream_t stream) {
    const float* coords = (const float*)d_in[0];
    const int*   gene   = (const int*)d_in[1];
    const float* w      = (const float*)d_in[2];
    const float* b      = (const float*)d_in[3];
    float*       out    = (float*)d_out;
    const int N = in_sizes[1];

    if (ws_size >= W5_BYTES && N >= 2) {
        unsigned char* w5 = (unsigned char*)d_ws;
        int total = N_GENES * 5;
        build_w5<<<(total + 255) / 256, 256, 0, stream>>>(w, b, w5);
        unsigned int H = ((unsigned)N + 1) / 2;
        long long threads = (long long)H * 5;
        int grid = (int)((threads + 255) / 256);
        frag_embed5x2<<<grid, 256, 0, stream>>>(coords, gene, w5, out,
                                                (unsigned)N, H);
    } else {
        frag_embed_fallback<<<(N + 255) / 256, 256, 0, stream>>>(coords, gene, w, b, out, N);
    }
}

// Round 13
// 21.556 us; speedup vs baseline: 1.2610x; 1.2610x over previous
//
#include <hip/hip_runtime.h>
#include <hip/hip_bf16.h>
#include <math.h>

// FragmentEmbedder, round 13: R11 structure (best: 25.3us) + targeted fixes.
//   * plain (non-nt) loads for coords/gene/table: nt on single-use streams is
//     pointless (compulsory miss) and may bypass L2 allocation; nt STOREs kept
//     to protect the 640KB table from 20MB of write allocation.
//   * LDS-transpose repack: coalesced float4 loads of 51 genes/block -> LDS ->
//     compute. Replaces the strided-scalar repack (~2-4us -> ~1us).
//   * main kernel block=1024 (4.9k blocks vs 19.5k): dispatch/tail overhead.
//
// Table layout per gene (128 B, R11):
//   @ +16c   : uint4 {(i=0,x),(i=1,x),(i=0,y),(i=1,y)} f16 sin/cos-pair weights
//   @ +80+8c : uint2 { half2(Lx,Ly), f32 bias' }
//   Lx,Ly = sum_{i>=2} f_i*w (sin-linearized, pre-summed)
//   bias' = bias + sum_{i>=2} cos-folded weights

#define N_GENES 5000
#define BLK_BYTES 128
#define W5_BYTES ((size_t)N_GENES * BLK_BYTES)    // 640 KB
#define GENES_PER_BLK 51

typedef _Float16 half2_t __attribute__((ext_vector_type(2)));

#if __has_builtin(__builtin_amdgcn_fdot2)
__device__ __forceinline__ float fdot2f(half2_t a, half2_t b, float c) {
    return __builtin_amdgcn_fdot2(a, b, c, false);
}
#else
__device__ __forceinline__ float fdot2f(half2_t a, half2_t b, float c) {
    return fmaf((float)a.x, (float)b.x, fmaf((float)a.y, (float)b.y, c));
}
#endif

__device__ __forceinline__ half2_t pkrtz(float a, float b) {
    auto r = __builtin_amdgcn_cvt_pkrtz(a, b);
    union { decltype(r) s; half2_t d; } v; v.s = r; return v.d;
}
__device__ __forceinline__ half2_t u2h(unsigned int u) {
    union { unsigned int i; half2_t h; } v; v.i = u; return v.h;
}
__device__ __forceinline__ float u2f(unsigned int u) {
    union { unsigned int i; float f; } v; v.i = u; return v.f;
}
__device__ __forceinline__ unsigned int h2u(_Float16 lo, _Float16 hi) {
    union { _Float16 h[2]; unsigned int i; } v; v.h[0] = lo; v.h[1] = hi; return v.i;
}
__device__ __forceinline__ unsigned int f2u(float f) {
    union { float f; unsigned int i; } v; v.f = f; return v.i;
}

// f_i = 10^{-0.6*(i+1)}, i = 0..9  (radians)
__device__ __constant__ float FRc[10] = {
    0.251188643150958f, 0.0630957344480193f, 0.0158489319246111f,
    0.00398107170553497f, 0.001f, 0.000251188643150958f,
    6.30957344480193e-05f, 1.58489319246111e-05f, 3.98107170553497e-06f, 1e-06f
};

// ---------------- pre-pass: LDS-transpose repack ----------------
__global__ __launch_bounds__(256) void build_w5_lds(
    const float* __restrict__ w,     // [5000, 40, 5]
    const float* __restrict__ bias,  // [5000, 5]
    unsigned char* __restrict__ w5)
{
    __shared__ float lds[GENES_PER_BLK * 200];
    const int g0 = blockIdx.x * GENES_PER_BLK;
    const int ng = (N_GENES - g0 < GENES_PER_BLK) ? (N_GENES - g0) : GENES_PER_BLK;

    // Phase 1: coalesced float4 load of ng*200 floats into LDS.
    const float4* __restrict__ src =
        reinterpret_cast<const float4*>(w + (size_t)g0 * 200);
    const int nf4 = ng * 50;
    for (int k = threadIdx.x; k < nf4; k += 256)
        reinterpret_cast<float4*>(lds)[k] = src[k];
    __syncthreads();

    // Phase 2: one thread per (gene_local, c).
    const int u = threadIdx.x;
    if (u >= ng * 5) return;
    const int gl = u / 5, c = u - 5 * gl;
    const int g = g0 + gl;
    const float* base = lds + gl * 200 + c;        // w[g][a][c] = base[a*5]

    uint4 S;
    S.x = h2u((_Float16)base[0 * 5],  (_Float16)base[1 * 5]);    // i=0, x
    S.y = h2u((_Float16)base[2 * 5],  (_Float16)base[3 * 5]);    // i=1, x
    S.z = h2u((_Float16)base[20 * 5], (_Float16)base[21 * 5]);   // i=0, y
    S.w = h2u((_Float16)base[22 * 5], (_Float16)base[23 * 5]);   // i=1, y

    float Lx = 0.f, Ly = 0.f;
    float bp = bias[(size_t)g * 5 + c];
#pragma unroll
    for (int i = 2; i < 10; ++i) {
        Lx += FRc[i] * base[(2 * i) * 5];
        Ly += FRc[i] * base[(20 + 2 * i) * 5];
        bp += base[(2 * i + 1) * 5] + base[(21 + 2 * i) * 5];
    }

    unsigned char* blk = w5 + (size_t)g * BLK_BYTES;
    *reinterpret_cast<uint4*>(blk + c * 16) = S;
    uint2 L;
    L.x = h2u((_Float16)Lx, (_Float16)Ly);
    L.y = f2u(bp);
    *reinterpret_cast<uint2*>(blk + 80 + c * 8) = L;
}

// sin/cos pair for freq I packed to half2 (I = 0,1 only; I>=2 folded away)
template <int I>
__device__ __forceinline__ half2_t sc_pack(float x) {
    float t = x * FRc[I];
    float s, co;
    if (I == 0) {
        s  = __sinf(t);                                            // |t| <= ~1.4
        co = __cosf(t);
    } else {                                                       // |t| <= 0.36
        float u = t * t;
        s  = t * fmaf(u, fmaf(u, 1.f / 120.f, -1.f / 6.f), 1.f);   // err < 5e-5
        co = fmaf(u, fmaf(u, 1.f / 24.f, -0.5f), 1.f);             // err < 1e-5
    }
    return pkrtz(s, co);
}

// ---------------- main: 5 lanes per point, 2 loads, 5 fdot2 ----------------
__global__ __launch_bounds__(1024) void frag_embed5(
    const float* __restrict__ coords,        // [N,2] flat
    const int*   __restrict__ gene_ix,       // [N]
    const unsigned char* __restrict__ w5,    // [5000] x 128 B blocks
    float*       __restrict__ out,           // [N, 5]
    unsigned int N)
{
    unsigned int tid = blockIdx.x * 1024u + threadIdx.x;
    unsigned int n = tid / 5u;           // point (magic-mul)
    unsigned int c = tid - n * 5u;       // output channel, 0..4
    if (n >= N) return;

    const float x = coords[2 * (size_t)n];
    const float y = coords[2 * (size_t)n + 1];
    const int g = gene_ix[n];

    // Gene block: the point's 5 lanes cover 2 cache lines, 3 requests total.
    const unsigned char* __restrict__ blk = w5 + (size_t)g * BLK_BYTES;
    const uint4 S = *reinterpret_cast<const uint4*>(blk + c * 16);
    const uint2 L = *reinterpret_cast<const uint2*>(blk + 80 + c * 8);

    half2_t sx0 = sc_pack<0>(x), sx1 = sc_pack<1>(x);
    half2_t sy0 = sc_pack<0>(y), sy1 = sc_pack<1>(y);
    half2_t xy  = pkrtz(x, y);

    float acc = u2f(L.y);                 // bias' (+ all folded cos terms)
    acc = fdot2f(sx0, u2h(S.x), acc);
    acc = fdot2f(sx1, u2h(S.y), acc);
    acc = fdot2f(sy0, u2h(S.z), acc);
    acc = fdot2f(sy1, u2h(S.w), acc);
    acc = fdot2f(xy,  u2h(L.x), acc);     // all i>=2 terms, pre-summed

    float r = 1.f / (1.f + __expf(-acc));
    __builtin_nontemporal_store(r, out + (size_t)n * 5 + c);
}

// ---------------- fallback if d_ws too small ----------------
__global__ __launch_bounds__(256) void frag_embed_fallback(
    const float* __restrict__ coords, const int* __restrict__ gene_ix,
    const float* __restrict__ weight, const float* __restrict__ bias,
    float* __restrict__ out, int N)
{
    int n = blockIdx.x * blockDim.x + threadIdx.x;
    if (n >= N) return;
    const float cxo = coords[2 * (size_t)n];
    const float cyo = coords[2 * (size_t)n + 1];
    const int g = gene_ix[n];
    float emb[40];
    float c2[2] = { cxo, cyo };
#pragma unroll
    for (int d = 0; d < 2; ++d)
#pragma unroll
        for (int i = 0; i < 10; ++i) {
            float t = c2[d] * FRc[i];
            emb[d * 20 + 2 * i]     = __sinf(t);
            emb[d * 20 + 2 * i + 1] = __cosf(t);
        }
    const float4* wp = reinterpret_cast<const float4*>(weight + (size_t)g * 200);
    float acc[5];
#pragma unroll
    for (int c = 0; c < 5; ++c) acc[c] = bias[(size_t)g * 5 + c];
#pragma unroll
    for (int j = 0; j < 50; ++j) {
        float4 wv = wp[j];
        const int k = 4 * j;
        acc[(k + 0) % 5] = fmaf(emb[(k + 0) / 5], wv.x, acc[(k + 0) % 5]);
        acc[(k + 1) % 5] = fmaf(emb[(k + 1) / 5], wv.y, acc[(k + 1) % 5]);
        acc[(k + 2) % 5] = fmaf(emb[(k + 2) / 5], wv.z, acc[(k + 2) % 5]);
        acc[(k + 3) % 5] = fmaf(emb[(k + 3) / 5], wv.w, acc[(k + 3) % 5]);
    }
    size_t ob = (size_t)n * 5;
#pragma unroll
    for (int c = 0; c < 5; ++c)
        out[ob + c] = 1.f / (1.f + __expf(-acc[c]));
}

extern "C" void kernel_launch(void* const* d_in, const int* in_sizes, int n_in,
                              void* d_out, int out_size, void* d_ws, size_t ws_size,
                              hipStream_t stream) {
    const float* coords = (const float*)d_in[0];
    const int*   gene   = (const int*)d_in[1];
    const float* w      = (const float*)d_in[2];
    const float* b      = (const float*)d_in[3];
    float*       out    = (float*)d_out;
    const int N = in_sizes[1];

    if (ws_size >= W5_BYTES) {
        unsigned char* w5 = (unsigned char*)d_ws;
        int rblocks = (N_GENES + GENES_PER_BLK - 1) / GENES_PER_BLK;
        build_w5_lds<<<rblocks, 256, 0, stream>>>(w, b, w5);
        long long threads = (long long)N * 5;
        int grid = (int)((threads + 1023) / 1024);
        frag_embed5<<<grid, 1024, 0, stream>>>(coords, gene, w5, out, (unsigned)N);
    } else {
        frag_embed_fallback<<<(N + 255) / 256, 256, 0, stream>>>(coords, gene, w, b, out, N);
    }
}

// Round 14
// 21.284 us; speedup vs baseline: 1.2772x; 1.0128x over previous
//
#include <hip/hip_runtime.h>
#include <hip/hip_bf16.h>
#include <math.h>

// FragmentEmbedder, round 14: LDS-shared sinusoids (compute once per point).
//
// R13 post-mortem: main kernel VALU-issue-bound; the 5 lanes of each point
// redundantly compute identical sin/cos (82 of ~150 cyc/wave, transcendentals
// are quarter-rate). R14:
//   * block (5,64): c = threadIdx.x, point y = threadIdx.y. No index division.
//   * lane c<4 computes task c of {sin,cos}(x*f0 | x*f1 | y*f0 | y*f1) via
//     uniform cndmask-selected input, packs f16 pair, writes lds[y][c].
//     One barrier; all 5 lanes read the 4 pairs back as one ds_read_b128.
//   * sigmoid negation folded into table (weights,bias pre-scaled by -1):
//     r = rcp(1 + __expf(acc)).
//
// Table layout per gene (128 B, R11, now negated):
//   @ +16c   : uint4 {-(i=0,x),-(i=1,x),-(i=0,y),-(i=1,y)} f16 pairs
//   @ +80+8c : uint2 { half2(-Lx,-Ly), f32 -bias' }

#define N_GENES 5000
#define BLK_BYTES 128
#define W5_BYTES ((size_t)N_GENES * BLK_BYTES)    // 640 KB
#define GENES_PER_BLK 51

typedef _Float16 half2_t __attribute__((ext_vector_type(2)));

#if __has_builtin(__builtin_amdgcn_fdot2)
__device__ __forceinline__ float fdot2f(half2_t a, half2_t b, float c) {
    return __builtin_amdgcn_fdot2(a, b, c, false);
}
#else
__device__ __forceinline__ float fdot2f(half2_t a, half2_t b, float c) {
    return fmaf((float)a.x, (float)b.x, fmaf((float)a.y, (float)b.y, c));
}
#endif

__device__ __forceinline__ half2_t pkrtz(float a, float b) {
    auto r = __builtin_amdgcn_cvt_pkrtz(a, b);
    union { decltype(r) s; half2_t d; } v; v.s = r; return v.d;
}
__device__ __forceinline__ half2_t u2h(unsigned int u) {
    union { unsigned int i; half2_t h; } v; v.i = u; return v.h;
}
__device__ __forceinline__ float u2f(unsigned int u) {
    union { unsigned int i; float f; } v; v.i = u; return v.f;
}
__device__ __forceinline__ unsigned int h2uu(half2_t h) {
    union { half2_t h; unsigned int i; } v; v.h = h; return v.i;
}
__device__ __forceinline__ unsigned int h2u(_Float16 lo, _Float16 hi) {
    union { _Float16 h[2]; unsigned int i; } v; v.h[0] = lo; v.h[1] = hi; return v.i;
}
__device__ __forceinline__ unsigned int f2u(float f) {
    union { float f; unsigned int i; } v; v.f = f; return v.i;
}

// f_i = 10^{-0.6*(i+1)}, i = 0..9  (radians)
__device__ __constant__ float FRc[10] = {
    0.251188643150958f, 0.0630957344480193f, 0.0158489319246111f,
    0.00398107170553497f, 0.001f, 0.000251188643150958f,
    6.30957344480193e-05f, 1.58489319246111e-05f, 3.98107170553497e-06f, 1e-06f
};

// ---------------- pre-pass: LDS-transpose repack (negated table) ----------------
__global__ __launch_bounds__(256) void build_w5_lds(
    const float* __restrict__ w,     // [5000, 40, 5]
    const float* __restrict__ bias,  // [5000, 5]
    unsigned char* __restrict__ w5)
{
    __shared__ float lds[GENES_PER_BLK * 200];
    const int g0 = blockIdx.x * GENES_PER_BLK;
    const int ng = (N_GENES - g0 < GENES_PER_BLK) ? (N_GENES - g0) : GENES_PER_BLK;

    const float4* __restrict__ src =
        reinterpret_cast<const float4*>(w + (size_t)g0 * 200);
    const int nf4 = ng * 50;
    for (int k = threadIdx.x; k < nf4; k += 256)
        reinterpret_cast<float4*>(lds)[k] = src[k];
    __syncthreads();

    const int u = threadIdx.x;
    if (u >= ng * 5) return;
    const int gl = u / 5, c = u - 5 * gl;
    const int g = g0 + gl;
    const float* base = lds + gl * 200 + c;        // w[g][a][c] = base[a*5]

    // NOTE: all values negated so the main kernel computes acc = -(w.e + b)
    // and sigmoid = rcp(1 + exp(acc)).
    uint4 S;
    S.x = h2u((_Float16)(-base[0 * 5]),  (_Float16)(-base[1 * 5]));    // i=0, x
    S.y = h2u((_Float16)(-base[2 * 5]),  (_Float16)(-base[3 * 5]));    // i=1, x
    S.z = h2u((_Float16)(-base[20 * 5]), (_Float16)(-base[21 * 5]));   // i=0, y
    S.w = h2u((_Float16)(-base[22 * 5]), (_Float16)(-base[23 * 5]));   // i=1, y

    float Lx = 0.f, Ly = 0.f;
    float bp = bias[(size_t)g * 5 + c];
#pragma unroll
    for (int i = 2; i < 10; ++i) {
        Lx += FRc[i] * base[(2 * i) * 5];
        Ly += FRc[i] * base[(20 + 2 * i) * 5];
        bp += base[(2 * i + 1) * 5] + base[(21 + 2 * i) * 5];
    }

    unsigned char* blk = w5 + (size_t)g * BLK_BYTES;
    *reinterpret_cast<uint4*>(blk + c * 16) = S;
    uint2 L;
    L.x = h2u((_Float16)(-Lx), (_Float16)(-Ly));
    L.y = f2u(-bp);
    *reinterpret_cast<uint2*>(blk + 80 + c * 8) = L;
}

// ---------------- main: block (5,64); sinusoids shared via LDS ----------------
__global__ __launch_bounds__(320) void frag_embed_sh(
    const float2* __restrict__ coords,       // [N]
    const int*   __restrict__ gene_ix,       // [N]
    const unsigned char* __restrict__ w5,    // [5000] x 128 B blocks
    float*       __restrict__ out,           // [N, 5]
    unsigned int N)
{
    __shared__ unsigned int sinpk[64][4];     // [point-in-block][task]

    const unsigned int c = threadIdx.x;       // 0..4
    const unsigned int y = threadIdx.y;       // 0..63
    unsigned int n = blockIdx.x * 64u + y;
    const bool valid = (n < N);
    if (!valid) n = N - 1;                    // clamp loads; predicate store

    const float2 xy2 = coords[n];
    const int g = gene_ix[n];

    // Gather this channel's table row (2 lines per point, 3 req/point).
    const unsigned char* __restrict__ blk = w5 + (size_t)g * BLK_BYTES;
    const uint4 S = *reinterpret_cast<const uint4*>(blk + c * 16);
    const uint2 L = *reinterpret_cast<const uint2*>(blk + 80 + c * 8);

    // Task (c&3): {x*f0, x*f1, y*f0, y*f1} -> packed (sin, cos) f16 pair.
    {
        const unsigned int task = c & 3u;
        const float in = (task & 2u) ? xy2.y : xy2.x;
        const float fr = (task & 1u) ? FRc[1] : FRc[0];
        const float t = in * fr;
        const float s = __sinf(t);
        const float co = __cosf(t);
        if (c < 4) sinpk[y][c] = h2uu(pkrtz(s, co));
    }
    __syncthreads();

    const uint4 P = *reinterpret_cast<const uint4*>(&sinpk[y][0]);
    const half2_t xyh = pkrtz(xy2.x, xy2.y);

    float acc = u2f(L.y);                 // -(bias' + folded cos terms)
    acc = fdot2f(u2h(P.x), u2h(S.x), acc);
    acc = fdot2f(u2h(P.y), u2h(S.y), acc);
    acc = fdot2f(u2h(P.z), u2h(S.z), acc);
    acc = fdot2f(u2h(P.w), u2h(S.w), acc);
    acc = fdot2f(xyh,      u2h(L.x), acc);   // i>=2 pre-summed (negated)

    // acc = -(w.e + b)  ->  sigmoid = 1 / (1 + e^acc)
    const float r = __frcp_rn(1.f + __expf(acc));
    if (valid)
        __builtin_nontemporal_store(r, out + (size_t)n * 5 + c);
}

// ---------------- fallback if d_ws too small ----------------
__global__ __launch_bounds__(256) void frag_embed_fallback(
    const float* __restrict__ coords, const int* __restrict__ gene_ix,
    const float* __restrict__ weight, const float* __restrict__ bias,
    float* __restrict__ out, int N)
{
    int n = blockIdx.x * blockDim.x + threadIdx.x;
    if (n >= N) return;
    const float cxo = coords[2 * (size_t)n];
    const float cyo = coords[2 * (size_t)n + 1];
    const int g = gene_ix[n];
    float emb[40];
    float c2[2] = { cxo, cyo };
#pragma unroll
    for (int d = 0; d < 2; ++d)
#pragma unroll
        for (int i = 0; i < 10; ++i) {
            float t = c2[d] * FRc[i];
            emb[d * 20 + 2 * i]     = __sinf(t);
            emb[d * 20 + 2 * i + 1] = __cosf(t);
        }
    const float4* wp = reinterpret_cast<const float4*>(weight + (size_t)g * 200);
    float acc[5];
#pragma unroll
    for (int c = 0; c < 5; ++c) acc[c] = bias[(size_t)g * 5 + c];
#pragma unroll
    for (int j = 0; j < 50; ++j) {
        float4 wv = wp[j];
        const int k = 4 * j;
        acc[(k + 0) % 5] = fmaf(emb[(k + 0) / 5], wv.x, acc[(k + 0) % 5]);
        acc[(k + 1) % 5] = fmaf(emb[(k + 1) / 5], wv.y, acc[(k + 1) % 5]);
        acc[(k + 2) % 5] = fmaf(emb[(k + 2) / 5], wv.z, acc[(k + 2) % 5]);
        acc[(k + 3) % 5] = fmaf(emb[(k + 3) / 5], wv.w, acc[(k + 3) % 5]);
    }
    size_t ob = (size_t)n * 5;
#pragma unroll
    for (int c = 0; c < 5; ++c)
        out[ob + c] = 1.f / (1.f + __expf(-acc[c]));
}

extern "C" void kernel_launch(void* const* d_in, const int* in_sizes, int n_in,
                              void* d_out, int out_size, void* d_ws, size_t ws_size,
                              hipStream_t stream) {
    const float* coords = (const float*)d_in[0];
    const int*   gene   = (const int*)d_in[1];
    const float* w      = (const float*)d_in[2];
    const float* b      = (const float*)d_in[3];
    float*       out    = (float*)d_out;
    const int N = in_sizes[1];

    if (ws_size >= W5_BYTES) {
        unsigned char* w5 = (unsigned char*)d_ws;
        int rblocks = (N_GENES + GENES_PER_BLK - 1) / GENES_PER_BLK;
        build_w5_lds<<<rblocks, 256, 0, stream>>>(w, b, w5);
        int grid = (N + 63) / 64;
        dim3 blk(5, 64);
        frag_embed_sh<<<grid, blk, 0, stream>>>((const float2*)coords, gene, w5,
                                                out, (unsigned)N);
    } else {
        frag_embed_fallback<<<(N + 255) / 256, 256, 0, stream>>>(coords, gene, w, b, out, N);
    }
}